// Round 12
// baseline (494.665 us; speedup 1.0000x reference)
//
#include <hip/hip_runtime.h>

#define NU 100000      // users
#define NI 50000       // items
#define NN 150000      // total nodes
#define DIM 128        // embedding dim
#define NP 1000000     // undirected pairs (edge k and k+NP are the two directions)
#define NB ((NN + 63) / 64)   // 2344 64-node buckets
#define NSH 32                // scatter shards (per-XCD pairs footprint 3.6MB < 4MB L2)
#define QSPLIT 16             // sub-blocks per shard (bucket mod-16 interleave)
#define QB ((NB + QSPLIT - 1) / QSPLIT)   // 147 LDS counters per sub-block
#define NSCT (NSH * QSPLIT)               // 512 scatter blocks
#define CAP 96                // slots per (shard,bucket) cell = 384B = 3 lines;
                              // lambda_item=40, lambda_user=20 -> P(ovfl) ~7e-13/cell
#define CAP4 (CAP / 4)        // 24 int4 chunks per cell
#define BCAP 4096             // adj entries reserved per bucket (64 nodes x 64)

typedef _Float16 half8 __attribute__((ext_vector_type(8)));
typedef _Float16 half4c __attribute__((ext_vector_type(4)));

#define PPS (NP / NSH)                    // 31250 pairs per shard (exact)
#define CVH 9375                          // convert blocks per build kernel (half each)
#define HALFE 9600000                     // elements in each convert half (NN*DIM/2)

// convert helper: one block converts 1024 consecutive floats starting at e0
__device__ __forceinline__ void convert_block(
    size_t e0, int t, const float* __restrict__ user,
    const float* __restrict__ item, _Float16* __restrict__ x16) {
    size_t e = e0 + (size_t)t * 4;
    if (e < (size_t)NN * DIM) {
        const size_t NUsz = (size_t)NU * DIM;
        float4 v = (e < NUsz) ? *(const float4*)(user + e)
                              : *(const float4*)(item + (e - NUsz));
        half4c h;
        h[0] = (_Float16)v.x; h[1] = (_Float16)v.y;
        h[2] = (_Float16)v.z; h[3] = (_Float16)v.w;
        *(half4c*)(x16 + e) = h;
    }
}

// ---------------- scatter: LDS-counter sharded scatter, 16-way split ----------------
// 512 blocks = 32 shards x 16 sub-blocks. Sub-block (s,q) scans shard s's pair
// slice, handles only directions with target bucket ≡ q (mod 16); its 147 cell
// counters live in LDS (zero global atomics). s=blk&31, q=blk>>5 puts all 16
// sub-blocks of a shard on ONE XCD (32%8==0, round-robin dispatch): the edge
// slice is L2-reread and — the round-12 fix — the shard's 900KB pairs region x
// 4 shards/XCD = 3.6MB fits the 4MB L2, so partial 384B cells fill in L2 and
// evict ONCE (round-11's 128-shard geometry was 4.8MB/XCD -> partial-line RMW
// thrash to HBM). Counter flush transposed (cfil[bucket][shard]). Trailing
// blocks stream half the fp32->fp16 convert under the scatter latency.
__global__ __launch_bounds__(256) void scatter_kernel(
    const int* __restrict__ row, const int* __restrict__ col,
    int* __restrict__ cfil, int* __restrict__ pairs,
    const float* __restrict__ user, const float* __restrict__ item,
    _Float16* __restrict__ x16) {
    int blk = blockIdx.x;
    int t = threadIdx.x;
    if (blk < NSCT) {
        __shared__ int lcnt[QB];
        int s = blk & (NSH - 1);
        int q = blk >> 5;
        for (int i = t; i < QB; i += 256) lcnt[i] = 0;
        __syncthreads();
        int base = s * PPS;
        int* pb = pairs + (size_t)s * NB * CAP;
        for (int i = t; i < PPS; i += 256) {
            int k = base + i;
            int u = row[k];          // user id (target of direction 2)
            int v = col[k];          // item id (target of direction 1)
            int c1 = v >> 6;
            if ((c1 & 15) == q) {
                int p1 = atomicAdd(&lcnt[c1 >> 4], 1);
                if (p1 < CAP) pb[c1 * CAP + p1] = (u << 6) | (v & 63);
            }
            int c2 = u >> 6;
            if ((c2 & 15) == q) {
                int p2 = atomicAdd(&lcnt[c2 >> 4], 1);
                if (p2 < CAP) pb[c2 * CAP + p2] = (v << 6) | (u & 63);
            }
        }
        __syncthreads();
        for (int i = t; i < QB; i += 256) {
            int b = (i << 4) | q;
            if (b < NB) cfil[b * NSH + s] = min(lcnt[i], CAP);
        }
    } else {
        convert_block((size_t)(blk - NSCT) * 1024, t, user, item, x16);
    }
}

// ---------------- place (+ fused fp16 convert, second half) ----------------
// Place blocks (blk < NB): stage the bucket's 32 cells (32 x 384B = 12 KB)
// into LDS as 768 int4 loads (fully line-granular), then count/scan/place
// entirely from LDS. Convert blocks (blk >= NB) stream the second half of x0
// under the place blocks' staging latency.
__global__ __launch_bounds__(256) void place_kernel(
    const int* __restrict__ cfil, const int* __restrict__ pairs,
    int* __restrict__ adj, int* __restrict__ ptr, int* __restrict__ deg,
    float* __restrict__ dinv,
    const float* __restrict__ user, const float* __restrict__ item,
    _Float16* __restrict__ x16) {
    __shared__ int lp[NSH * CAP];   // 12 KB staged slots
    __shared__ int llen[NSH];
    __shared__ int lcnt[64];
    __shared__ int lptr[64];
    __shared__ int lfill[64];
    int blk = blockIdx.x;
    int t = threadIdx.x;
    if (blk < NB) {
        int b = blk;
        if (t < NSH) llen[t] = cfil[b * NSH + t];
        if (t < 64) { lcnt[t] = 0; lfill[t] = 0; }
        __syncthreads();
        // stage: int4 idx in [0, NSH*CAP4): cell ci = idx/CAP4, chunk j = idx%CAP4
        int4* lp4 = (int4*)lp;
        #pragma unroll
        for (int p = 0; p < 3; p++) {
            int idx = p * 256 + t;      // NSH*CAP4 = 768 exactly
            int ci = idx / CAP4;
            int j = idx - ci * CAP4;
            lp4[idx] = ((const int4*)pairs)[((size_t)ci * NB + b) * CAP4 + j];
        }
        __syncthreads();
        // count (from LDS)
        for (int slot = t; slot < NSH * CAP; slot += 256) {
            int s = slot / CAP;
            int i = slot - s * CAP;
            if (i < llen[s])
                atomicAdd(&lcnt[lp[slot] & 63], 1);
        }
        __syncthreads();
        if (t < 64) {   // threads 0..63 = lanes 0..63 of wave 0
            int v = lcnt[t];
            int incl = v;
            #pragma unroll
            for (int off = 1; off < 64; off <<= 1) {
                int u = __shfl_up(incl, off, 64);
                if (t >= off) incl += u;
            }
            lptr[t] = (b << 12) + incl - v;   // bucket's static adj base + prefix
            int c = (b << 6) + t;
            if (c < NN) {
                ptr[c] = lptr[t];
                deg[c] = v;
                dinv[c] = (v > 0) ? 1.0f / sqrtf((float)v) : 0.0f;
            }
        }
        __syncthreads();
        // place (from LDS)
        for (int slot = t; slot < NSH * CAP; slot += 256) {
            int s = slot / CAP;
            int i = slot - s * CAP;
            if (i < llen[s]) {
                int pk = lp[slot];
                int lc = pk & 63;
                int so = lptr[lc] + atomicAdd(&lfill[lc], 1);
                adj[so] = pk >> 6;
            }
        }
    } else {
        convert_block((size_t)HALFE + (size_t)(blk - NB) * 1024, t, user, item, x16);
    }
}

// ---------------- propagation (wide-gather, unroll-2) ----------------
// One wave per target node. 16 lanes cover one 256B row (8 halves/lane);
// 4 quads x 2 unrolled slots = 8 edges / iteration, 16 lines in flight.
// fp32 accumulate; fabric-roofline-bound (~3.58 TB/s effective, FETCH ~= 287 MB
// ~= per-XCD distinct-coverage floor with private L2s). Plain loads/stores
// only — nt hints measured net-negative here (round 4: 104 -> 116 us).
__global__ __launch_bounds__(256) void prop_kernel(
    const _Float16* __restrict__ xin,
    const float* __restrict__ dinv, const int* __restrict__ ptr,
    const int* __restrict__ deg, const int* __restrict__ adj,
    _Float16* __restrict__ xout, int finalize,
    const _Float16* __restrict__ x0, const _Float16* __restrict__ x1,
    const _Float16* __restrict__ x2, float* __restrict__ out)
{
    int wid = (blockIdx.x * blockDim.x + threadIdx.x) >> 6;
    if (wid >= NN) return;
    int lane = threadIdx.x & 63;
    int q = lane >> 4;     // edge sub-slot 0..3
    int m = lane & 15;     // halves [8m, 8m+8) of the row
    int beg = ptr[wid];
    int end = beg + deg[wid];

    float a0 = 0.f, a1 = 0.f, a2 = 0.f, a3 = 0.f;
    float a4 = 0.f, a5 = 0.f, a6 = 0.f, a7 = 0.f;
    int j = beg;
    for (; j + 8 <= end; j += 8) {
        int r0 = adj[j + q];
        int r1 = adj[j + 4 + q];
        float w0 = dinv[r0];
        float w1 = dinv[r1];
        half8 v0 = *(const half8*)(xin + (size_t)r0 * DIM + 8 * m);
        half8 v1 = *(const half8*)(xin + (size_t)r1 * DIM + 8 * m);
        a0 += w0 * (float)v0[0] + w1 * (float)v1[0];
        a1 += w0 * (float)v0[1] + w1 * (float)v1[1];
        a2 += w0 * (float)v0[2] + w1 * (float)v1[2];
        a3 += w0 * (float)v0[3] + w1 * (float)v1[3];
        a4 += w0 * (float)v0[4] + w1 * (float)v1[4];
        a5 += w0 * (float)v0[5] + w1 * (float)v1[5];
        a6 += w0 * (float)v0[6] + w1 * (float)v1[6];
        a7 += w0 * (float)v0[7] + w1 * (float)v1[7];
    }
    if (j < end) {
        int jj0 = j + q;
        int jj1 = j + 4 + q;
        int r0 = adj[min(jj0, end - 1)];
        int r1 = adj[min(jj1, end - 1)];
        float w0 = (jj0 < end) ? dinv[r0] : 0.f;
        float w1 = (jj1 < end) ? dinv[r1] : 0.f;
        half8 v0 = *(const half8*)(xin + (size_t)r0 * DIM + 8 * m);
        half8 v1 = *(const half8*)(xin + (size_t)r1 * DIM + 8 * m);
        a0 += w0 * (float)v0[0] + w1 * (float)v1[0];
        a1 += w0 * (float)v0[1] + w1 * (float)v1[1];
        a2 += w0 * (float)v0[2] + w1 * (float)v1[2];
        a3 += w0 * (float)v0[3] + w1 * (float)v1[3];
        a4 += w0 * (float)v0[4] + w1 * (float)v1[4];
        a5 += w0 * (float)v0[5] + w1 * (float)v1[5];
        a6 += w0 * (float)v0[6] + w1 * (float)v1[6];
        a7 += w0 * (float)v0[7] + w1 * (float)v1[7];
    }
    a0 += __shfl_xor(a0, 16, 64); a1 += __shfl_xor(a1, 16, 64);
    a2 += __shfl_xor(a2, 16, 64); a3 += __shfl_xor(a3, 16, 64);
    a4 += __shfl_xor(a4, 16, 64); a5 += __shfl_xor(a5, 16, 64);
    a6 += __shfl_xor(a6, 16, 64); a7 += __shfl_xor(a7, 16, 64);
    a0 += __shfl_xor(a0, 32, 64); a1 += __shfl_xor(a1, 32, 64);
    a2 += __shfl_xor(a2, 32, 64); a3 += __shfl_xor(a3, 32, 64);
    a4 += __shfl_xor(a4, 32, 64); a5 += __shfl_xor(a5, 32, 64);
    a6 += __shfl_xor(a6, 32, 64); a7 += __shfl_xor(a7, 32, 64);

    if (q != 0) return;
    float dc = dinv[wid];
    float n0 = dc * a0, n1 = dc * a1, n2 = dc * a2, n3 = dc * a3;
    float n4 = dc * a4, n5 = dc * a5, n6 = dc * a6, n7 = dc * a7;

    if (!finalize) {
        half8 h;
        h[0] = (_Float16)n0; h[1] = (_Float16)n1; h[2] = (_Float16)n2; h[3] = (_Float16)n3;
        h[4] = (_Float16)n4; h[5] = (_Float16)n5; h[6] = (_Float16)n6; h[7] = (_Float16)n7;
        *(half8*)(xout + (size_t)wid * DIM + 8 * m) = h;
    } else {
        size_t base = (size_t)wid * DIM + 8 * m;
        half8 f0 = *(const half8*)(x0 + base);
        half8 f1 = *(const half8*)(x1 + base);
        half8 f2 = *(const half8*)(x2 + base);
        float* po = out + base;
        float4 oa, ob;
        oa.x = ((float)f0[0] + (float)f1[0] + (float)f2[0] + n0) * 0.25f;
        oa.y = ((float)f0[1] + (float)f1[1] + (float)f2[1] + n1) * 0.25f;
        oa.z = ((float)f0[2] + (float)f1[2] + (float)f2[2] + n2) * 0.25f;
        oa.w = ((float)f0[3] + (float)f1[3] + (float)f2[3] + n3) * 0.25f;
        ob.x = ((float)f0[4] + (float)f1[4] + (float)f2[4] + n4) * 0.25f;
        ob.y = ((float)f0[5] + (float)f1[5] + (float)f2[5] + n5) * 0.25f;
        ob.z = ((float)f0[6] + (float)f1[6] + (float)f2[6] + n6) * 0.25f;
        ob.w = ((float)f0[7] + (float)f1[7] + (float)f2[7] + n7) * 0.25f;
        *(float4*)(po) = oa;
        *(float4*)(po + 4) = ob;
    }
}

// ---------------- launch ----------------

extern "C" void kernel_launch(void* const* d_in, const int* in_sizes, int n_in,
                              void* d_out, int out_size, void* d_ws, size_t ws_size,
                              hipStream_t stream) {
    const int* edge = (const int*)d_in[0];      // [2, NE] int32
    const int* row = edge;                      // sources (first NP entries = users)
    const int* col = edge + 2 * NP;             // targets (first NP entries = items)
    const float* user = (const float*)d_in[1];  // [NU, DIM]
    const float* item = (const float*)d_in[2];  // [NI, DIM]
    float* out = (float*)d_out;                 // [NN, DIM]

    char* ws = (char*)d_ws;
    size_t off = 0;
    auto alloc = [&](size_t bytes) -> void* {
        void* p = ws + off;
        off = (off + bytes + 255) & ~(size_t)255;
        return p;
    };
    _Float16* x0 = (_Float16*)alloc(sizeof(_Float16) * (size_t)NN * DIM);  // 38.4 MB
    _Float16* x1 = (_Float16*)alloc(sizeof(_Float16) * (size_t)NN * DIM);
    _Float16* x2 = (_Float16*)alloc(sizeof(_Float16) * (size_t)NN * DIM);
    float* dinv = (float*)alloc(sizeof(float) * NN);
    int*   cfil = (int*)  alloc(sizeof(int) * NB * NSH);              // 300 KB (written by scatter)
    int*   ptr  = (int*)  alloc(sizeof(int) * NN);
    int*   deg  = (int*)  alloc(sizeof(int) * NN);
    int*   pairs= (int*)  alloc(sizeof(int) * (size_t)NSH * NB * CAP);// 28.8 MB
    int*   adj  = (int*)  alloc(sizeof(int) * (size_t)NB * BCAP);     // 38.4 MB

    scatter_kernel<<<NSCT + CVH, 256, 0, stream>>>(row, col, cfil, pairs,
                                                   user, item, x0);
    place_kernel<<<NB + CVH, 256, 0, stream>>>(cfil, pairs, adj, ptr, deg, dinv,
                                               user, item, x0);

    int blocks = (NN + 3) / 4;  // 4 waves (nodes) per 256-thread block
    prop_kernel<<<blocks, 256, 0, stream>>>(x0, dinv, ptr, deg, adj, x1, 0,
                                            nullptr, nullptr, nullptr, nullptr);
    prop_kernel<<<blocks, 256, 0, stream>>>(x1, dinv, ptr, deg, adj, x2, 0,
                                            nullptr, nullptr, nullptr, nullptr);
    prop_kernel<<<blocks, 256, 0, stream>>>(x2, dinv, ptr, deg, adj, nullptr, 1,
                                            x0, x1, x2, out);
}

// Round 13
// 476.920 us; speedup vs baseline: 1.0372x; 1.0372x over previous
//
#include <hip/hip_runtime.h>

#define NU 100000      // users
#define NI 50000       // items
#define NN 150000      // total nodes
#define DIM 128        // embedding dim
#define NP 1000000     // undirected pairs (edge k and k+NP are the two directions)
#define NB ((NN + 63) / 64)   // 2344 64-node buckets
#define NSH 128               // scatter shards
#define QSPLIT 8              // sub-blocks per shard (bucket mod-8 interleave)
#define QB ((NB + QSPLIT - 1) / QSPLIT)   // 293 LDS counters per sub-block
#define NSCT (NSH * QSPLIT)               // 1024 scatter blocks
#define CAP 32                // slots per (shard,bucket) cell = one 128B line
#define BCAP 4096             // adj entries reserved per bucket (64 nodes x 64)

typedef _Float16 half8 __attribute__((ext_vector_type(8)));
typedef _Float16 half4c __attribute__((ext_vector_type(4)));

#define PPS ((NP + NSH - 1) / NSH)        // 7813 pairs per shard
#define CVH 9375                          // convert blocks per build kernel (half each)
#define HALFE 9600000                     // elements in each convert half (NN*DIM/2)

// prop grid: bipartite XCD segregation. Block blk -> XCD blk%8 (round-robin).
// XCDs 0-3 take user targets (gather ONLY the 12.8MB item sub-table);
// XCDs 4-7 take item targets (gather ONLY the 25.6MB user sub-table).
// Each half carries 1M edges -> 250K edges/XCD, edge-balanced.
#define UBLK (NU / 4)         // 25000 user blocks (4 nodes each)
#define IBLK (NI / 4)         // 12500 item blocks
#define PGRP 6250             // ceil(UBLK/4) >= ceil(IBLK/4)
#define PROPG (PGRP * 8)      // 50000 prop blocks

// convert helper: one block converts 1024 consecutive floats starting at e0
__device__ __forceinline__ void convert_block(
    size_t e0, int t, const float* __restrict__ user,
    const float* __restrict__ item, _Float16* __restrict__ x16) {
    size_t e = e0 + (size_t)t * 4;
    if (e < (size_t)NN * DIM) {
        const size_t NUsz = (size_t)NU * DIM;
        float4 v = (e < NUsz) ? *(const float4*)(user + e)
                              : *(const float4*)(item + (e - NUsz));
        half4c h;
        h[0] = (_Float16)v.x; h[1] = (_Float16)v.y;
        h[2] = (_Float16)v.z; h[3] = (_Float16)v.w;
        *(half4c*)(x16 + e) = h;
    }
}

// ---------------- scatter: LDS-counter sharded scatter, 8-way split (round-11) ----
__global__ __launch_bounds__(256) void scatter_kernel(
    const int* __restrict__ row, const int* __restrict__ col,
    int* __restrict__ cfil, int* __restrict__ pairs,
    const float* __restrict__ user, const float* __restrict__ item,
    _Float16* __restrict__ x16) {
    int blk = blockIdx.x;
    int t = threadIdx.x;
    if (blk < NSCT) {
        __shared__ int lcnt[QB];
        int s = blk & (NSH - 1);
        int q = blk >> 7;
        for (int i = t; i < QB; i += 256) lcnt[i] = 0;
        __syncthreads();
        int base = s * PPS;
        int lim = min(NP - base, PPS);
        int* pb = pairs + (size_t)s * NB * CAP;
        for (int i = t; i < lim; i += 256) {
            int k = base + i;
            int u = row[k];          // user id (target of direction 2)
            int v = col[k];          // item id (target of direction 1)
            int c1 = v >> 6;
            if ((c1 & 7) == q) {
                int p1 = atomicAdd(&lcnt[c1 >> 3], 1);
                if (p1 < CAP) pb[c1 * CAP + p1] = (u << 6) | (v & 63);
            }
            int c2 = u >> 6;
            if ((c2 & 7) == q) {
                int p2 = atomicAdd(&lcnt[c2 >> 3], 1);
                if (p2 < CAP) pb[c2 * CAP + p2] = (v << 6) | (u & 63);
            }
        }
        __syncthreads();
        for (int i = t; i < QB; i += 256) {
            int b = (i << 3) | q;
            if (b < NB) cfil[b * NSH + s] = min(lcnt[i], CAP);
        }
    } else {
        convert_block((size_t)(blk - NSCT) * 1024, t, user, item, x16);
    }
}

// ---------------- place (+ fused fp16 convert, second half) (round-11) ----------
__global__ __launch_bounds__(256) void place_kernel(
    const int* __restrict__ cfil, const int* __restrict__ pairs,
    int* __restrict__ adj, int* __restrict__ ptr, int* __restrict__ deg,
    float* __restrict__ dinv,
    const float* __restrict__ user, const float* __restrict__ item,
    _Float16* __restrict__ x16) {
    __shared__ int lp[NSH * CAP];   // 16 KB staged slots
    __shared__ int llen[NSH];
    __shared__ int lcnt[64];
    __shared__ int lptr[64];
    __shared__ int lfill[64];
    int blk = blockIdx.x;
    int t = threadIdx.x;
    if (blk < NB) {
        int b = blk;
        if (t < NSH) llen[t] = cfil[b * NSH + t];
        if (t < 64) { lcnt[t] = 0; lfill[t] = 0; }
        __syncthreads();
        // stage: int4 idx -> cell ci = idx>>3, chunk j = idx&7
        int4* lp4 = (int4*)lp;
        #pragma unroll
        for (int p = 0; p < 4; p++) {
            int idx = p * 256 + t;
            int ci = idx >> 3;
            int j = idx & 7;
            lp4[idx] = ((const int4*)pairs)[(((size_t)ci * NB + b) << 3) + j];
        }
        __syncthreads();
        // count (from LDS)
        #pragma unroll
        for (int slot = t; slot < NSH * CAP; slot += 256) {
            if ((slot & 31) < llen[slot >> 5])
                atomicAdd(&lcnt[lp[slot] & 63], 1);
        }
        __syncthreads();
        if (t < 64) {   // threads 0..63 = lanes 0..63 of wave 0
            int v = lcnt[t];
            int incl = v;
            #pragma unroll
            for (int off = 1; off < 64; off <<= 1) {
                int u = __shfl_up(incl, off, 64);
                if (t >= off) incl += u;
            }
            lptr[t] = (b << 12) + incl - v;   // bucket's static adj base + prefix
            int c = (b << 6) + t;
            if (c < NN) {
                ptr[c] = lptr[t];
                deg[c] = v;
                dinv[c] = (v > 0) ? 1.0f / sqrtf((float)v) : 0.0f;
            }
        }
        __syncthreads();
        // place (from LDS)
        #pragma unroll
        for (int slot = t; slot < NSH * CAP; slot += 256) {
            if ((slot & 31) < llen[slot >> 5]) {
                int pk = lp[slot];
                int lc = pk & 63;
                int so = lptr[lc] + atomicAdd(&lfill[lc], 1);
                adj[so] = pk >> 6;
            }
        }
    } else {
        convert_block((size_t)HALFE + (size_t)(blk - NB) * 1024, t, user, item, x16);
    }
}

// ---------------- propagation (wide-gather, unroll-2, bipartite-segregated) ------
// One wave per target node. 16 lanes cover one 256B row (8 halves/lane);
// 4 quads x 2 unrolled slots = 8 edges / iteration, 16 lines in flight.
// Bipartite XCD segregation (round-13): XCDs 0-3 do user targets (item-row
// gathers only, 12.8MB sub-table), XCDs 4-7 do item targets (user-row gathers,
// 25.6MB). Shrinks each XCD's gather working set vs the 38.4MB mixed table ->
// higher L2 hit rate -> less L2-miss fabric traffic (was 287MB at 44% hit).
// Mapping drift costs only speed. Plain loads/stores (nt is net-negative, r4).
__global__ __launch_bounds__(256) void prop_kernel(
    const _Float16* __restrict__ xin,
    const float* __restrict__ dinv, const int* __restrict__ ptr,
    const int* __restrict__ deg, const int* __restrict__ adj,
    _Float16* __restrict__ xout, int finalize,
    const _Float16* __restrict__ x0, const _Float16* __restrict__ x1,
    const _Float16* __restrict__ x2, float* __restrict__ out)
{
    int blk = blockIdx.x;
    int g = blk >> 3;
    int r = blk & 7;
    int base;
    if (r < 4) {                 // user-target side (XCDs 0-3)
        int ui = g * 4 + r;
        if (ui >= UBLK) return;
        base = ui << 2;
    } else {                     // item-target side (XCDs 4-7)
        int ii = g * 4 + (r - 4);
        if (ii >= IBLK) return;
        base = NU + (ii << 2);
    }
    int wid = base + ((int)threadIdx.x >> 6);
    int lane = threadIdx.x & 63;
    int q = lane >> 4;     // edge sub-slot 0..3
    int m = lane & 15;     // halves [8m, 8m+8) of the row
    int beg = ptr[wid];
    int end = beg + deg[wid];

    float a0 = 0.f, a1 = 0.f, a2 = 0.f, a3 = 0.f;
    float a4 = 0.f, a5 = 0.f, a6 = 0.f, a7 = 0.f;
    int j = beg;
    for (; j + 8 <= end; j += 8) {
        int r0 = adj[j + q];
        int r1 = adj[j + 4 + q];
        float w0 = dinv[r0];
        float w1 = dinv[r1];
        half8 v0 = *(const half8*)(xin + (size_t)r0 * DIM + 8 * m);
        half8 v1 = *(const half8*)(xin + (size_t)r1 * DIM + 8 * m);
        a0 += w0 * (float)v0[0] + w1 * (float)v1[0];
        a1 += w0 * (float)v0[1] + w1 * (float)v1[1];
        a2 += w0 * (float)v0[2] + w1 * (float)v1[2];
        a3 += w0 * (float)v0[3] + w1 * (float)v1[3];
        a4 += w0 * (float)v0[4] + w1 * (float)v1[4];
        a5 += w0 * (float)v0[5] + w1 * (float)v1[5];
        a6 += w0 * (float)v0[6] + w1 * (float)v1[6];
        a7 += w0 * (float)v0[7] + w1 * (float)v1[7];
    }
    if (j < end) {
        int jj0 = j + q;
        int jj1 = j + 4 + q;
        int r0 = adj[min(jj0, end - 1)];
        int r1 = adj[min(jj1, end - 1)];
        float w0 = (jj0 < end) ? dinv[r0] : 0.f;
        float w1 = (jj1 < end) ? dinv[r1] : 0.f;
        half8 v0 = *(const half8*)(xin + (size_t)r0 * DIM + 8 * m);
        half8 v1 = *(const half8*)(xin + (size_t)r1 * DIM + 8 * m);
        a0 += w0 * (float)v0[0] + w1 * (float)v1[0];
        a1 += w0 * (float)v0[1] + w1 * (float)v1[1];
        a2 += w0 * (float)v0[2] + w1 * (float)v1[2];
        a3 += w0 * (float)v0[3] + w1 * (float)v1[3];
        a4 += w0 * (float)v0[4] + w1 * (float)v1[4];
        a5 += w0 * (float)v0[5] + w1 * (float)v1[5];
        a6 += w0 * (float)v0[6] + w1 * (float)v1[6];
        a7 += w0 * (float)v0[7] + w1 * (float)v1[7];
    }
    a0 += __shfl_xor(a0, 16, 64); a1 += __shfl_xor(a1, 16, 64);
    a2 += __shfl_xor(a2, 16, 64); a3 += __shfl_xor(a3, 16, 64);
    a4 += __shfl_xor(a4, 16, 64); a5 += __shfl_xor(a5, 16, 64);
    a6 += __shfl_xor(a6, 16, 64); a7 += __shfl_xor(a7, 16, 64);
    a0 += __shfl_xor(a0, 32, 64); a1 += __shfl_xor(a1, 32, 64);
    a2 += __shfl_xor(a2, 32, 64); a3 += __shfl_xor(a3, 32, 64);
    a4 += __shfl_xor(a4, 32, 64); a5 += __shfl_xor(a5, 32, 64);
    a6 += __shfl_xor(a6, 32, 64); a7 += __shfl_xor(a7, 32, 64);

    if (q != 0) return;
    float dc = dinv[wid];
    float n0 = dc * a0, n1 = dc * a1, n2 = dc * a2, n3 = dc * a3;
    float n4 = dc * a4, n5 = dc * a5, n6 = dc * a6, n7 = dc * a7;

    if (!finalize) {
        half8 h;
        h[0] = (_Float16)n0; h[1] = (_Float16)n1; h[2] = (_Float16)n2; h[3] = (_Float16)n3;
        h[4] = (_Float16)n4; h[5] = (_Float16)n5; h[6] = (_Float16)n6; h[7] = (_Float16)n7;
        *(half8*)(xout + (size_t)wid * DIM + 8 * m) = h;
    } else {
        size_t bb = (size_t)wid * DIM + 8 * m;
        half8 f0 = *(const half8*)(x0 + bb);
        half8 f1 = *(const half8*)(x1 + bb);
        half8 f2 = *(const half8*)(x2 + bb);
        float* po = out + bb;
        float4 oa, ob;
        oa.x = ((float)f0[0] + (float)f1[0] + (float)f2[0] + n0) * 0.25f;
        oa.y = ((float)f0[1] + (float)f1[1] + (float)f2[1] + n1) * 0.25f;
        oa.z = ((float)f0[2] + (float)f1[2] + (float)f2[2] + n2) * 0.25f;
        oa.w = ((float)f0[3] + (float)f1[3] + (float)f2[3] + n3) * 0.25f;
        ob.x = ((float)f0[4] + (float)f1[4] + (float)f2[4] + n4) * 0.25f;
        ob.y = ((float)f0[5] + (float)f1[5] + (float)f2[5] + n5) * 0.25f;
        ob.z = ((float)f0[6] + (float)f1[6] + (float)f2[6] + n6) * 0.25f;
        ob.w = ((float)f0[7] + (float)f1[7] + (float)f2[7] + n7) * 0.25f;
        *(float4*)(po) = oa;
        *(float4*)(po + 4) = ob;
    }
}

// ---------------- launch ----------------

extern "C" void kernel_launch(void* const* d_in, const int* in_sizes, int n_in,
                              void* d_out, int out_size, void* d_ws, size_t ws_size,
                              hipStream_t stream) {
    const int* edge = (const int*)d_in[0];      // [2, NE] int32
    const int* row = edge;                      // sources (first NP entries = users)
    const int* col = edge + 2 * NP;             // targets (first NP entries = items)
    const float* user = (const float*)d_in[1];  // [NU, DIM]
    const float* item = (const float*)d_in[2];  // [NI, DIM]
    float* out = (float*)d_out;                 // [NN, DIM]

    char* ws = (char*)d_ws;
    size_t off = 0;
    auto alloc = [&](size_t bytes) -> void* {
        void* p = ws + off;
        off = (off + bytes + 255) & ~(size_t)255;
        return p;
    };
    _Float16* x0 = (_Float16*)alloc(sizeof(_Float16) * (size_t)NN * DIM);  // 38.4 MB
    _Float16* x1 = (_Float16*)alloc(sizeof(_Float16) * (size_t)NN * DIM);
    _Float16* x2 = (_Float16*)alloc(sizeof(_Float16) * (size_t)NN * DIM);
    float* dinv = (float*)alloc(sizeof(float) * NN);
    int*   cfil = (int*)  alloc(sizeof(int) * NB * NSH);              // 1.2 MB (written by scatter)
    int*   ptr  = (int*)  alloc(sizeof(int) * NN);
    int*   deg  = (int*)  alloc(sizeof(int) * NN);
    int*   pairs= (int*)  alloc(sizeof(int) * (size_t)NSH * NB * CAP);// 38.4 MB
    int*   adj  = (int*)  alloc(sizeof(int) * (size_t)NB * BCAP);     // 38.4 MB

    scatter_kernel<<<NSCT + CVH, 256, 0, stream>>>(row, col, cfil, pairs,
                                                   user, item, x0);
    place_kernel<<<NB + CVH, 256, 0, stream>>>(cfil, pairs, adj, ptr, deg, dinv,
                                               user, item, x0);

    prop_kernel<<<PROPG, 256, 0, stream>>>(x0, dinv, ptr, deg, adj, x1, 0,
                                           nullptr, nullptr, nullptr, nullptr);
    prop_kernel<<<PROPG, 256, 0, stream>>>(x1, dinv, ptr, deg, adj, x2, 0,
                                           nullptr, nullptr, nullptr, nullptr);
    prop_kernel<<<PROPG, 256, 0, stream>>>(x2, dinv, ptr, deg, adj, nullptr, 1,
                                           x0, x1, x2, out);
}

// Round 14
// 450.730 us; speedup vs baseline: 1.0975x; 1.0581x over previous
//
#include <hip/hip_runtime.h>

#define NU 100000      // users
#define NI 50000       // items
#define NN 150000      // total nodes
#define DIM 128        // embedding dim
#define NP 1000000     // undirected pairs (edge k and k+NP are the two directions)
#define NB ((NN + 63) / 64)   // 2344 64-node buckets
#define NSH 128               // scatter shards
#define QSPLIT 8              // sub-blocks per shard (bucket mod-8 interleave)
#define QB ((NB + QSPLIT - 1) / QSPLIT)   // 293 LDS counters per sub-block
#define NSCT (NSH * QSPLIT)               // 1024 scatter blocks
#define CAP 32                // slots per (shard,bucket) cell = one 128B line
#define BCAP 4096             // adj entries reserved per bucket (64 nodes x 64)

typedef _Float16 half8 __attribute__((ext_vector_type(8)));
typedef _Float16 half4c __attribute__((ext_vector_type(4)));

#define PPS ((NP + NSH - 1) / NSH)        // 7813 pairs per shard
#define CVH 9375                          // convert blocks per build kernel (half each)
#define HALFE 9600000                     // elements in each convert half (NN*DIM/2)

// convert helper: one block converts 1024 consecutive floats starting at e0
__device__ __forceinline__ void convert_block(
    size_t e0, int t, const float* __restrict__ user,
    const float* __restrict__ item, _Float16* __restrict__ x16) {
    size_t e = e0 + (size_t)t * 4;
    if (e < (size_t)NN * DIM) {
        const size_t NUsz = (size_t)NU * DIM;
        float4 v = (e < NUsz) ? *(const float4*)(user + e)
                              : *(const float4*)(item + (e - NUsz));
        half4c h;
        h[0] = (_Float16)v.x; h[1] = (_Float16)v.y;
        h[2] = (_Float16)v.z; h[3] = (_Float16)v.w;
        *(half4c*)(x16 + e) = h;
    }
}

// ---------------- scatter: LDS-counter sharded scatter, 8-way split ----------------
// 1024 blocks = 128 shards x 8 sub-blocks. Sub-block (s,q) scans shard s's pair
// slice, handles only directions with target bucket ≡ q (mod 8); its 293 cell
// counters live in LDS (zero global atomics). s=blk&127, q=blk>>7 puts all 8
// sub-blocks of a shard on ONE XCD (128%8==0, round-robin dispatch): edge
// re-reads are L2-hits, pairs region stays XCD-local. Counter flush transposed
// (cfil[bucket][shard]) for place's coalesced read. Trailing blocks stream
// half the fp32->fp16 convert under the scatter latency.
__global__ __launch_bounds__(256) void scatter_kernel(
    const int* __restrict__ row, const int* __restrict__ col,
    int* __restrict__ cfil, int* __restrict__ pairs,
    const float* __restrict__ user, const float* __restrict__ item,
    _Float16* __restrict__ x16) {
    int blk = blockIdx.x;
    int t = threadIdx.x;
    if (blk < NSCT) {
        __shared__ int lcnt[QB];
        int s = blk & (NSH - 1);
        int q = blk >> 7;
        for (int i = t; i < QB; i += 256) lcnt[i] = 0;
        __syncthreads();
        int base = s * PPS;
        int lim = min(NP - base, PPS);
        int* pb = pairs + (size_t)s * NB * CAP;
        for (int i = t; i < lim; i += 256) {
            int k = base + i;
            int u = row[k];          // user id (target of direction 2)
            int v = col[k];          // item id (target of direction 1)
            int c1 = v >> 6;
            if ((c1 & 7) == q) {
                int p1 = atomicAdd(&lcnt[c1 >> 3], 1);
                if (p1 < CAP) pb[c1 * CAP + p1] = (u << 6) | (v & 63);
            }
            int c2 = u >> 6;
            if ((c2 & 7) == q) {
                int p2 = atomicAdd(&lcnt[c2 >> 3], 1);
                if (p2 < CAP) pb[c2 * CAP + p2] = (v << 6) | (u & 63);
            }
        }
        __syncthreads();
        for (int i = t; i < QB; i += 256) {
            int b = (i << 3) | q;
            if (b < NB) cfil[b * NSH + s] = min(lcnt[i], CAP);
        }
    } else {
        convert_block((size_t)(blk - NSCT) * 1024, t, user, item, x16);
    }
}

// ---------------- place (+ fused fp16 convert, second half) ----------------
// Place blocks (blk < NB): stage the bucket's 128 cells (128 x 128B = 16 KB)
// into LDS as 1024 int4 loads (fully line-granular), then count/scan/place
// entirely from LDS. Convert blocks (blk >= NB) stream the second half of x0
// under the place blocks' staging latency.
__global__ __launch_bounds__(256) void place_kernel(
    const int* __restrict__ cfil, const int* __restrict__ pairs,
    int* __restrict__ adj, int* __restrict__ ptr, int* __restrict__ deg,
    float* __restrict__ dinv,
    const float* __restrict__ user, const float* __restrict__ item,
    _Float16* __restrict__ x16) {
    __shared__ int lp[NSH * CAP];   // 16 KB staged slots
    __shared__ int llen[NSH];
    __shared__ int lcnt[64];
    __shared__ int lptr[64];
    __shared__ int lfill[64];
    int blk = blockIdx.x;
    int t = threadIdx.x;
    if (blk < NB) {
        int b = blk;
        if (t < NSH) llen[t] = cfil[b * NSH + t];
        if (t < 64) { lcnt[t] = 0; lfill[t] = 0; }
        __syncthreads();
        // stage: int4 idx -> cell ci = idx>>3, chunk j = idx&7
        int4* lp4 = (int4*)lp;
        #pragma unroll
        for (int p = 0; p < 4; p++) {
            int idx = p * 256 + t;
            int ci = idx >> 3;
            int j = idx & 7;
            lp4[idx] = ((const int4*)pairs)[(((size_t)ci * NB + b) << 3) + j];
        }
        __syncthreads();
        // count (from LDS)
        #pragma unroll
        for (int slot = t; slot < NSH * CAP; slot += 256) {
            if ((slot & 31) < llen[slot >> 5])
                atomicAdd(&lcnt[lp[slot] & 63], 1);
        }
        __syncthreads();
        if (t < 64) {   // threads 0..63 = lanes 0..63 of wave 0
            int v = lcnt[t];
            int incl = v;
            #pragma unroll
            for (int off = 1; off < 64; off <<= 1) {
                int u = __shfl_up(incl, off, 64);
                if (t >= off) incl += u;
            }
            lptr[t] = (b << 12) + incl - v;   // bucket's static adj base + prefix
            int c = (b << 6) + t;
            if (c < NN) {
                ptr[c] = lptr[t];
                deg[c] = v;
                dinv[c] = (v > 0) ? 1.0f / sqrtf((float)v) : 0.0f;
            }
        }
        __syncthreads();
        // place (from LDS)
        #pragma unroll
        for (int slot = t; slot < NSH * CAP; slot += 256) {
            if ((slot & 31) < llen[slot >> 5]) {
                int pk = lp[slot];
                int lc = pk & 63;
                int so = lptr[lc] + atomicAdd(&lfill[lc], 1);
                adj[so] = pk >> 6;
            }
        }
    } else {
        convert_block((size_t)HALFE + (size_t)(blk - NB) * 1024, t, user, item, x16);
    }
}

// ---------------- propagation (wide-gather, unroll-2) ----------------
// One wave per target node. 16 lanes cover one 256B row (8 halves/lane);
// 4 quads x 2 unrolled slots = 8 edges / iteration, 16 lines in flight.
// fp32 accumulate; fabric-roofline-bound: 3.58 TB/s effective, FETCH ~= 287 MB
// ~= 8-XCD compulsory coverage of the 38.4MB table (random bipartite gather,
// private 4MB L2s — segregation (r13) and nt hints (r4) both measured counter-
// productive; linear wid mapping is best).
__global__ __launch_bounds__(256) void prop_kernel(
    const _Float16* __restrict__ xin,
    const float* __restrict__ dinv, const int* __restrict__ ptr,
    const int* __restrict__ deg, const int* __restrict__ adj,
    _Float16* __restrict__ xout, int finalize,
    const _Float16* __restrict__ x0, const _Float16* __restrict__ x1,
    const _Float16* __restrict__ x2, float* __restrict__ out)
{
    int wid = (blockIdx.x * blockDim.x + threadIdx.x) >> 6;
    if (wid >= NN) return;
    int lane = threadIdx.x & 63;
    int q = lane >> 4;     // edge sub-slot 0..3
    int m = lane & 15;     // halves [8m, 8m+8) of the row
    int beg = ptr[wid];
    int end = beg + deg[wid];

    float a0 = 0.f, a1 = 0.f, a2 = 0.f, a3 = 0.f;
    float a4 = 0.f, a5 = 0.f, a6 = 0.f, a7 = 0.f;
    int j = beg;
    for (; j + 8 <= end; j += 8) {
        int r0 = adj[j + q];
        int r1 = adj[j + 4 + q];
        float w0 = dinv[r0];
        float w1 = dinv[r1];
        half8 v0 = *(const half8*)(xin + (size_t)r0 * DIM + 8 * m);
        half8 v1 = *(const half8*)(xin + (size_t)r1 * DIM + 8 * m);
        a0 += w0 * (float)v0[0] + w1 * (float)v1[0];
        a1 += w0 * (float)v0[1] + w1 * (float)v1[1];
        a2 += w0 * (float)v0[2] + w1 * (float)v1[2];
        a3 += w0 * (float)v0[3] + w1 * (float)v1[3];
        a4 += w0 * (float)v0[4] + w1 * (float)v1[4];
        a5 += w0 * (float)v0[5] + w1 * (float)v1[5];
        a6 += w0 * (float)v0[6] + w1 * (float)v1[6];
        a7 += w0 * (float)v0[7] + w1 * (float)v1[7];
    }
    if (j < end) {
        int jj0 = j + q;
        int jj1 = j + 4 + q;
        int r0 = adj[min(jj0, end - 1)];
        int r1 = adj[min(jj1, end - 1)];
        float w0 = (jj0 < end) ? dinv[r0] : 0.f;
        float w1 = (jj1 < end) ? dinv[r1] : 0.f;
        half8 v0 = *(const half8*)(xin + (size_t)r0 * DIM + 8 * m);
        half8 v1 = *(const half8*)(xin + (size_t)r1 * DIM + 8 * m);
        a0 += w0 * (float)v0[0] + w1 * (float)v1[0];
        a1 += w0 * (float)v0[1] + w1 * (float)v1[1];
        a2 += w0 * (float)v0[2] + w1 * (float)v1[2];
        a3 += w0 * (float)v0[3] + w1 * (float)v1[3];
        a4 += w0 * (float)v0[4] + w1 * (float)v1[4];
        a5 += w0 * (float)v0[5] + w1 * (float)v1[5];
        a6 += w0 * (float)v0[6] + w1 * (float)v1[6];
        a7 += w0 * (float)v0[7] + w1 * (float)v1[7];
    }
    a0 += __shfl_xor(a0, 16, 64); a1 += __shfl_xor(a1, 16, 64);
    a2 += __shfl_xor(a2, 16, 64); a3 += __shfl_xor(a3, 16, 64);
    a4 += __shfl_xor(a4, 16, 64); a5 += __shfl_xor(a5, 16, 64);
    a6 += __shfl_xor(a6, 16, 64); a7 += __shfl_xor(a7, 16, 64);
    a0 += __shfl_xor(a0, 32, 64); a1 += __shfl_xor(a1, 32, 64);
    a2 += __shfl_xor(a2, 32, 64); a3 += __shfl_xor(a3, 32, 64);
    a4 += __shfl_xor(a4, 32, 64); a5 += __shfl_xor(a5, 32, 64);
    a6 += __shfl_xor(a6, 32, 64); a7 += __shfl_xor(a7, 32, 64);

    if (q != 0) return;
    float dc = dinv[wid];
    float n0 = dc * a0, n1 = dc * a1, n2 = dc * a2, n3 = dc * a3;
    float n4 = dc * a4, n5 = dc * a5, n6 = dc * a6, n7 = dc * a7;

    if (!finalize) {
        half8 h;
        h[0] = (_Float16)n0; h[1] = (_Float16)n1; h[2] = (_Float16)n2; h[3] = (_Float16)n3;
        h[4] = (_Float16)n4; h[5] = (_Float16)n5; h[6] = (_Float16)n6; h[7] = (_Float16)n7;
        *(half8*)(xout + (size_t)wid * DIM + 8 * m) = h;
    } else {
        size_t base = (size_t)wid * DIM + 8 * m;
        half8 f0 = *(const half8*)(x0 + base);
        half8 f1 = *(const half8*)(x1 + base);
        half8 f2 = *(const half8*)(x2 + base);
        float* po = out + base;
        float4 oa, ob;
        oa.x = ((float)f0[0] + (float)f1[0] + (float)f2[0] + n0) * 0.25f;
        oa.y = ((float)f0[1] + (float)f1[1] + (float)f2[1] + n1) * 0.25f;
        oa.z = ((float)f0[2] + (float)f1[2] + (float)f2[2] + n2) * 0.25f;
        oa.w = ((float)f0[3] + (float)f1[3] + (float)f2[3] + n3) * 0.25f;
        ob.x = ((float)f0[4] + (float)f1[4] + (float)f2[4] + n4) * 0.25f;
        ob.y = ((float)f0[5] + (float)f1[5] + (float)f2[5] + n5) * 0.25f;
        ob.z = ((float)f0[6] + (float)f1[6] + (float)f2[6] + n6) * 0.25f;
        ob.w = ((float)f0[7] + (float)f1[7] + (float)f2[7] + n7) * 0.25f;
        *(float4*)(po) = oa;
        *(float4*)(po + 4) = ob;
    }
}

// ---------------- launch ----------------

extern "C" void kernel_launch(void* const* d_in, const int* in_sizes, int n_in,
                              void* d_out, int out_size, void* d_ws, size_t ws_size,
                              hipStream_t stream) {
    const int* edge = (const int*)d_in[0];      // [2, NE] int32
    const int* row = edge;                      // sources (first NP entries = users)
    const int* col = edge + 2 * NP;             // targets (first NP entries = items)
    const float* user = (const float*)d_in[1];  // [NU, DIM]
    const float* item = (const float*)d_in[2];  // [NI, DIM]
    float* out = (float*)d_out;                 // [NN, DIM]

    char* ws = (char*)d_ws;
    size_t off = 0;
    auto alloc = [&](size_t bytes) -> void* {
        void* p = ws + off;
        off = (off + bytes + 255) & ~(size_t)255;
        return p;
    };
    _Float16* x0 = (_Float16*)alloc(sizeof(_Float16) * (size_t)NN * DIM);  // 38.4 MB
    _Float16* x1 = (_Float16*)alloc(sizeof(_Float16) * (size_t)NN * DIM);
    _Float16* x2 = (_Float16*)alloc(sizeof(_Float16) * (size_t)NN * DIM);
    float* dinv = (float*)alloc(sizeof(float) * NN);
    int*   cfil = (int*)  alloc(sizeof(int) * NB * NSH);              // 1.2 MB (written by scatter)
    int*   ptr  = (int*)  alloc(sizeof(int) * NN);
    int*   deg  = (int*)  alloc(sizeof(int) * NN);
    int*   pairs= (int*)  alloc(sizeof(int) * (size_t)NSH * NB * CAP);// 38.4 MB
    int*   adj  = (int*)  alloc(sizeof(int) * (size_t)NB * BCAP);     // 38.4 MB

    scatter_kernel<<<NSCT + CVH, 256, 0, stream>>>(row, col, cfil, pairs,
                                                   user, item, x0);
    place_kernel<<<NB + CVH, 256, 0, stream>>>(cfil, pairs, adj, ptr, deg, dinv,
                                               user, item, x0);

    int blocks = (NN + 3) / 4;  // 4 waves (nodes) per 256-thread block
    prop_kernel<<<blocks, 256, 0, stream>>>(x0, dinv, ptr, deg, adj, x1, 0,
                                            nullptr, nullptr, nullptr, nullptr);
    prop_kernel<<<blocks, 256, 0, stream>>>(x1, dinv, ptr, deg, adj, x2, 0,
                                            nullptr, nullptr, nullptr, nullptr);
    prop_kernel<<<blocks, 256, 0, stream>>>(x2, dinv, ptr, deg, adj, nullptr, 1,
                                            x0, x1, x2, out);
}